// Round 3
// baseline (810.759 us; speedup 1.0000x reference)
//
#include <hip/hip_runtime.h>
#include <hip/hip_bf16.h>
#include <stdint.h>

#define TOKS 2048
#define DHID 2048
#define NEXP 8
#define FR 1408
#define FS 2816
#define RSCALE 2.5f

typedef float f32x4 __attribute__((ext_vector_type(4)));
typedef short s16x8 __attribute__((ext_vector_type(8)));

#define SWZB(c) (((c) ^ ((c) >> 2)) & 7)

__device__ __forceinline__ ushort f2bf(float f) {
  union { __hip_bfloat16 b; ushort u; } v;
  v.b = __float2bfloat16(f);
  return v.u;
}

// ---------------- router: scores, top-2 weights, fused x->bf16 ----------------
__global__ __launch_bounds__(256) void k_router(
    const float* __restrict__ x, const float* __restrict__ wr,
    ushort* __restrict__ xb, int* __restrict__ top_e, float* __restrict__ top_w) {
  const int wid = threadIdx.x >> 6, lane = threadIdx.x & 63;
  const int t = blockIdx.x * 4 + wid;
  const float* xrow = x + (size_t)t * DHID;
  float acc[NEXP];
#pragma unroll
  for (int e = 0; e < NEXP; ++e) acc[e] = 0.f;
#pragma unroll 4
  for (int j = 0; j < DHID / 64; ++j) {
    const int k = j * 64 + lane;
    const float xv = xrow[k];
    xb[(size_t)t * DHID + k] = f2bf(xv);
    const float4 w0 = *(const float4*)(wr + (size_t)k * 8);
    const float4 w1 = *(const float4*)(wr + (size_t)k * 8 + 4);
    acc[0] += xv * w0.x; acc[1] += xv * w0.y; acc[2] += xv * w0.z; acc[3] += xv * w0.w;
    acc[4] += xv * w1.x; acc[5] += xv * w1.y; acc[6] += xv * w1.z; acc[7] += xv * w1.w;
  }
#pragma unroll
  for (int e = 0; e < NEXP; ++e) {
#pragma unroll
    for (int off = 32; off; off >>= 1) acc[e] += __shfl_xor(acc[e], off);
  }
  if (lane == 0) {
    int i1 = 0;
#pragma unroll
    for (int e = 1; e < NEXP; ++e) if (acc[e] > acc[i1]) i1 = e;
    int i2 = (i1 == 0) ? 1 : 0;
#pragma unroll
    for (int e = 0; e < NEXP; ++e) if (e != i1 && acc[e] > acc[i2]) i2 = e;
    const float w1 = 1.f / (1.f + expf(acc[i2] - acc[i1]));
    top_e[2 * t] = i1; top_e[2 * t + 1] = i2;
    top_w[2 * t] = w1; top_w[2 * t + 1] = 1.f - w1;
  }
}

// ---------------- per-expert token lists ----------------
__global__ __launch_bounds__(256) void k_lists(
    const int* __restrict__ top_e, const float* __restrict__ top_w,
    int* __restrict__ offs, int* __restrict__ ptok, float* __restrict__ pw) {
  __shared__ int cnt[NEXP], fill[NEXP], loff[NEXP + 1];
  const int tid = threadIdx.x;
  if (tid < NEXP) { cnt[tid] = 0; fill[tid] = 0; }
  __syncthreads();
  for (int p = tid; p < 2 * TOKS; p += 256) atomicAdd(&cnt[top_e[p]], 1);
  __syncthreads();
  if (tid == 0) {
    loff[0] = 0;
    for (int e = 0; e < NEXP; ++e) loff[e + 1] = loff[e] + cnt[e];
  }
  __syncthreads();
  for (int p = tid; p < 2 * TOKS; p += 256) {
    const int e = top_e[p];
    const int pos = loff[e] + atomicAdd(&fill[e], 1);
    ptok[pos] = p >> 1;
    pw[pos] = top_w[p];
  }
  if (tid < NEXP + 1) offs[tid] = loff[tid];
}

// ---------------- GEMM1: H = silu(A*Bg) * (A*Bu) ----------------
// tile 128x128, 4 waves (2x2), BK=64.
// A in LDS [128 rows][64 k] bf16, addr = row*128 + ((k/8 ^ (row&7))*16).
// B in LDS transposed: [128 cols][64 k] bf16, addr = c*128 + ((k/8 ^ SWZB(c))*16).
// Both operand frags are then plain k-contiguous ds_read_b128.
template<bool GATHER>
__global__ __launch_bounds__(256, 2) void k_gemm1(
    const ushort* __restrict__ A, const float* __restrict__ Bg_all,
    const float* __restrict__ Bu_all, ushort* __restrict__ H,
    const int* __restrict__ offs, const int* __restrict__ ptok,
    const int N, const int nTilesN) {
  constexpr int K = DHID;
  const int bid = blockIdx.x;
  const int mt = bid & 15;
  const int nt = (bid >> 4) % nTilesN;
  const int e  = (bid >> 4) / nTilesN;
  int base = 0, count = TOKS;
  if (GATHER) { base = offs[e]; count = offs[e + 1] - base; }
  if (mt * 128 >= count) return;
  const float* __restrict__ Bg = Bg_all + (size_t)e * K * N;
  const float* __restrict__ Bu = Bu_all + (size_t)e * K * N;

  __shared__ char smem[49152];  // 16384 A + 16384 Bg + 16384 Bu

  const int tid = threadIdx.x, lane = tid & 63, wid = tid >> 6;
  const int wm = wid >> 1, wn = wid & 1;

  // ---- A staging map (4 rows per thread) ----
  const int aj = tid & 7;
  const ushort* aptr[4];
  uint32_t alds[4];
#pragma unroll
  for (int i = 0; i < 4; ++i) {
    const int row = i * 32 + (tid >> 3);
    const int gr = mt * 128 + row;
    int arow;
    if (GATHER) arow = ptok[base + (gr < count ? gr : count - 1)];
    else arow = gr;
    aptr[i] = A + (size_t)arow * K + aj * 8;
    alds[i] = (uint32_t)(row * 128 + ((aj ^ (row & 7)) * 16));
  }

  // ---- B staging map: thread handles cols c4*4..+3, k-slot ks (8 k) ----
  const int c4 = tid & 31, ks = tid >> 5;
  const size_t bgbase = (size_t)ks * 8 * N + nt * 128 + c4 * 4;
  uint32_t blds[4];
#pragma unroll
  for (int cc = 0; cc < 4; ++cc) {
    const int c = c4 * 4 + cc;
    blds[cc] = (uint32_t)(c * 128 + ((ks ^ SWZB(c)) * 16));
  }

  const f32x4 fz = {0.f, 0.f, 0.f, 0.f};
  f32x4 accg[4][4], accu[4][4];
#pragma unroll
  for (int mi = 0; mi < 4; ++mi)
#pragma unroll
    for (int ni = 0; ni < 4; ++ni) { accg[mi][ni] = fz; accu[mi][ni] = fz; }

  for (int k0 = 0; k0 < K; k0 += 64) {
#pragma unroll
    for (int i = 0; i < 4; ++i) {
      const s16x8 v = *(const s16x8*)(aptr[i] + k0);
      *(s16x8*)(smem + alds[i]) = v;
    }
    {
      ushort gv[4][8], uv[4][8];
#pragma unroll
      for (int j = 0; j < 8; ++j) {
        const float4 g = *(const float4*)(Bg + (size_t)k0 * N + bgbase + (size_t)j * N);
        gv[0][j] = f2bf(g.x); gv[1][j] = f2bf(g.y); gv[2][j] = f2bf(g.z); gv[3][j] = f2bf(g.w);
      }
#pragma unroll
      for (int j = 0; j < 8; ++j) {
        const float4 u = *(const float4*)(Bu + (size_t)k0 * N + bgbase + (size_t)j * N);
        uv[0][j] = f2bf(u.x); uv[1][j] = f2bf(u.y); uv[2][j] = f2bf(u.z); uv[3][j] = f2bf(u.w);
      }
#pragma unroll
      for (int cc = 0; cc < 4; ++cc) {
        *(s16x8*)(smem + 16384 + blds[cc]) = *(const s16x8*)&gv[cc][0];
        *(s16x8*)(smem + 32768 + blds[cc]) = *(const s16x8*)&uv[cc][0];
      }
    }
    __syncthreads();
#pragma unroll
    for (int kk = 0; kk < 64; kk += 32) {
      s16x8 af[4];
#pragma unroll
      for (int mi = 0; mi < 4; ++mi) {
        const int row = wm * 64 + mi * 16 + (lane & 15);
        const int slot = (kk >> 3) + (lane >> 4);
        af[mi] = *(const s16x8*)(smem + row * 128 + ((slot ^ (row & 7)) * 16));
      }
#pragma unroll
      for (int ni = 0; ni < 4; ++ni) {
        const int colg = wn * 64 + ni * 16 + (lane & 15);
        const int slot = (kk >> 3) + (lane >> 4);
        const uint32_t boff = (uint32_t)(colg * 128 + ((slot ^ SWZB(colg)) * 16));
        const s16x8 bg = *(const s16x8*)(smem + 16384 + boff);
        const s16x8 bu = *(const s16x8*)(smem + 32768 + boff);
#pragma unroll
        for (int mi = 0; mi < 4; ++mi) {
          accg[mi][ni] = __builtin_amdgcn_mfma_f32_16x16x32_bf16(af[mi], bg, accg[mi][ni], 0, 0, 0);
          accu[mi][ni] = __builtin_amdgcn_mfma_f32_16x16x32_bf16(af[mi], bu, accu[mi][ni], 0, 0, 0);
        }
      }
    }
    __syncthreads();
  }

#pragma unroll
  for (int mi = 0; mi < 4; ++mi) {
    const int gr0 = mt * 128 + wm * 64 + mi * 16 + ((lane >> 4) << 2);
#pragma unroll
    for (int ni = 0; ni < 4; ++ni) {
      const int nc = nt * 128 + wn * 64 + ni * 16 + (lane & 15);
#pragma unroll
      for (int r = 0; r < 4; ++r) {
        const int gr = gr0 + r;
        if (!GATHER || gr < count) {
          const float g = accg[mi][ni][r];
          const float u = accu[mi][ni][r];
          const float h = g / (1.f + __expf(-g)) * u;
          H[(size_t)(base + gr) * N + nc] = f2bf(h);
        }
      }
    }
  }
}

// ---------------- GEMM2: out[token] += scale * (H * B_down) ----------------
template<bool ROUTED>
__global__ __launch_bounds__(256, 2) void k_gemm2(
    const ushort* __restrict__ Hbuf, const float* __restrict__ B_all,
    float* __restrict__ out, const int* __restrict__ offs,
    const int* __restrict__ ptok, const float* __restrict__ pw, const int K) {
  const int bid = blockIdx.x;
  const int mt = bid & 15, nt = (bid >> 4) & 15, e = bid >> 8;
  int base = 0, count = TOKS;
  if (ROUTED) { base = offs[e]; count = offs[e + 1] - base; }
  if (mt * 128 >= count) return;
  const float* __restrict__ B = B_all + (size_t)e * K * DHID;

  __shared__ char smem[32768];  // 16384 A + 16384 B
  const int tid = threadIdx.x, lane = tid & 63, wid = tid >> 6;
  const int wm = wid >> 1, wn = wid & 1;

  const int aj = tid & 7;
  const ushort* aptr[4];
  uint32_t alds[4];
#pragma unroll
  for (int i = 0; i < 4; ++i) {
    const int row = i * 32 + (tid >> 3);
    const int gr = mt * 128 + row;
    const int ar = base + (gr < count ? gr : count - 1);
    aptr[i] = Hbuf + (size_t)ar * K + aj * 8;
    alds[i] = (uint32_t)(row * 128 + ((aj ^ (row & 7)) * 16));
  }

  const int c4 = tid & 31, ks = tid >> 5;
  const size_t bbase = (size_t)ks * 8 * DHID + nt * 128 + c4 * 4;
  uint32_t blds[4];
#pragma unroll
  for (int cc = 0; cc < 4; ++cc) {
    const int c = c4 * 4 + cc;
    blds[cc] = (uint32_t)(c * 128 + ((ks ^ SWZB(c)) * 16));
  }

  const f32x4 fz = {0.f, 0.f, 0.f, 0.f};
  f32x4 acc[4][4];
#pragma unroll
  for (int mi = 0; mi < 4; ++mi)
#pragma unroll
    for (int ni = 0; ni < 4; ++ni) acc[mi][ni] = fz;

  for (int k0 = 0; k0 < K; k0 += 64) {
#pragma unroll
    for (int i = 0; i < 4; ++i) {
      const s16x8 v = *(const s16x8*)(aptr[i] + k0);
      *(s16x8*)(smem + alds[i]) = v;
    }
    {
      ushort bv[4][8];
#pragma unroll
      for (int j = 0; j < 8; ++j) {
        const float4 b = *(const float4*)(B + (size_t)k0 * DHID + bbase + (size_t)j * DHID);
        bv[0][j] = f2bf(b.x); bv[1][j] = f2bf(b.y); bv[2][j] = f2bf(b.z); bv[3][j] = f2bf(b.w);
      }
#pragma unroll
      for (int cc = 0; cc < 4; ++cc)
        *(s16x8*)(smem + 16384 + blds[cc]) = *(const s16x8*)&bv[cc][0];
    }
    __syncthreads();
#pragma unroll
    for (int kk = 0; kk < 64; kk += 32) {
      s16x8 af[4];
#pragma unroll
      for (int mi = 0; mi < 4; ++mi) {
        const int row = wm * 64 + mi * 16 + (lane & 15);
        const int slot = (kk >> 3) + (lane >> 4);
        af[mi] = *(const s16x8*)(smem + row * 128 + ((slot ^ (row & 7)) * 16));
      }
#pragma unroll
      for (int ni = 0; ni < 4; ++ni) {
        const int colg = wn * 64 + ni * 16 + (lane & 15);
        const int slot = (kk >> 3) + (lane >> 4);
        const uint32_t boff = (uint32_t)(colg * 128 + ((slot ^ SWZB(colg)) * 16));
        const s16x8 bb = *(const s16x8*)(smem + 16384 + boff);
#pragma unroll
        for (int mi = 0; mi < 4; ++mi)
          acc[mi][ni] = __builtin_amdgcn_mfma_f32_16x16x32_bf16(af[mi], bb, acc[mi][ni], 0, 0, 0);
      }
    }
    __syncthreads();
  }

#pragma unroll
  for (int mi = 0; mi < 4; ++mi) {
    const int gr0 = mt * 128 + wm * 64 + mi * 16 + ((lane >> 4) << 2);
#pragma unroll
    for (int ni = 0; ni < 4; ++ni) {
      const int nc = nt * 128 + wn * 64 + ni * 16 + (lane & 15);
#pragma unroll
      for (int r = 0; r < 4; ++r) {
        const int gr = gr0 + r;
        if (gr < count) {
          const int arow = base + gr;
          const float s = ROUTED ? (RSCALE * pw[arow]) : 1.f;
          const int tok = ROUTED ? ptok[arow] : gr;
          unsafeAtomicAdd(out + (size_t)tok * DHID + nc, acc[mi][ni][r] * s);
        }
      }
    }
  }
}

extern "C" void kernel_launch(void* const* d_in, const int* in_sizes, int n_in,
                              void* d_out, int out_size, void* d_ws, size_t ws_size,
                              hipStream_t stream) {
  const float* x   = (const float*)d_in[0];
  const float* wr  = (const float*)d_in[1];
  const float* wg  = (const float*)d_in[2];
  const float* wu  = (const float*)d_in[3];
  const float* wd  = (const float*)d_in[4];
  const float* wsg = (const float*)d_in[5];
  const float* wsu = (const float*)d_in[6];
  const float* wsd = (const float*)d_in[7];
  float* out = (float*)d_out;

  uint8_t* p = (uint8_t*)d_ws;
  ushort* xb   = (ushort*)p; p += (size_t)TOKS * DHID * 2;
  int* top_e   = (int*)p;    p += (size_t)2 * TOKS * 4;
  float* top_w = (float*)p;  p += (size_t)2 * TOKS * 4;
  int* offs    = (int*)p;    p += 256;
  int* ptok    = (int*)p;    p += (size_t)2 * TOKS * 4;
  float* pw    = (float*)p;  p += (size_t)2 * TOKS * 4;
  ushort* Hr   = (ushort*)p; p += (size_t)2 * TOKS * FR * 2;
  ushort* Hs   = (ushort*)p; p += (size_t)TOKS * FS * 2;

  hipMemsetAsync(d_out, 0, (size_t)out_size * sizeof(float), stream);
  k_router<<<TOKS / 4, 256, 0, stream>>>(x, wr, xb, top_e, top_w);
  k_lists<<<1, 256, 0, stream>>>(top_e, top_w, offs, ptok, pw);
  k_gemm1<true><<<NEXP * 11 * 16, 256, 0, stream>>>(xb, wg, wu, Hr, offs, ptok, FR, 11);
  k_gemm1<false><<<22 * 16, 256, 0, stream>>>(xb, wsg, wsu, Hs, offs, ptok, FS, 22);
  k_gemm2<true><<<NEXP * 16 * 16, 256, 0, stream>>>(Hr, wd, out, offs, ptok, pw, FR);
  k_gemm2<false><<<16 * 16, 256, 0, stream>>>(Hs, wsd, out, offs, ptok, pw, FS);
}